// Round 5
// baseline (742.534 us; speedup 1.0000x reference)
//
#include <hip/hip_runtime.h>

#define SEQ   512
#define BATCH 256
#define INDIM 784
#define NC4   196   // INDIM / 4
#define WCOLS 112   // columns per staging window (784 = 7 * 112); 448B/row contiguous
#define NWIN  7
#define HROWS 128   // rows per producer block (half a timestep)
#define PSTR  129   // LDS row stride in floats (odd -> conflict-free column reads)
#define HID   10
#define PF    16    // scan prefetch depth (steps)
#define SEG   256   // timesteps per scan segment (= producer phase size)
#define XIP   16    // padded xi row stride (floats)

typedef float f4 __attribute__((ext_vector_type(4)));
typedef float f2 __attribute__((ext_vector_type(2)));

static __device__ __forceinline__ f2 mk2(float a, float b) {
    f2 r; r[0] = a; r[1] = b; return r;
}

// ---------------------------------------------------------------------------
// Producer half-block: rows [row0, row0+128) of xi (row = t*BATCH + b).
// 256 threads = 128 rows x 2 j-halves; thread (r = tid&127, jh = tid>>7)
// accumulates 5 outputs for its row. jh is wave-uniform (waves 0,1 -> jh 0;
// waves 2,3 -> jh 1) so W reads stay scalar (SMEM pipe).
// x staged through LDS TRANSPOSED in 112-column windows: each row's global
// read run is 448B contiguous (4-5 cache lines, ~1.21x fetch vs 2.5 lines
// for the old 224B windows' 1.43x). Register prefetch of the next window
// (14 f4/thread) overlaps global latency with compute.
// LDS bank checks: write (4c4+q)*129 + rr -> stride 129 odd, <=2-way (free);
// compute read lds[c*129 + r] -> banks (c+r)%32, 64 lanes / 32 banks = 2-way.
// ---------------------------------------------------------------------------
__device__ __forceinline__ void produce_half(
    const float* __restrict__ x, const float* __restrict__ Wih,
    const float* __restrict__ bih, const float* __restrict__ bhh,
    float* __restrict__ xi, float* lds, long row0)
{
    const int tid = threadIdx.x;
    const int r   = tid & (HROWS - 1);
    const int jh  = tid >> 7;
    const int j0  = jh * 5;
    const f4* x4 = (const f4*)x + row0 * NC4;

    float acc[5];
#pragma unroll
    for (int jj = 0; jj < 5; ++jj) acc[jj] = bih[j0 + jj] + bhh[j0 + jj];

    f4 stg[14];
    // preload window 0: 128 rows x 28 f4 = 3584 f4 over 256 threads
#pragma unroll
    for (int k = 0; k < 14; ++k) {
        const int idx = k * 256 + tid;
        const int c4 = idx % 28, rr = idx / 28;
        stg[k] = x4[(long)rr * NC4 + c4];
    }

    for (int w = 0; w < NWIN; ++w) {
        // staged regs -> LDS, transposed
#pragma unroll
        for (int k = 0; k < 14; ++k) {
            const int idx = k * 256 + tid;
            const int c4 = idx % 28, rr = idx / 28;
            const int cb = c4 * 4;
            lds[(cb + 0) * PSTR + rr] = stg[k][0];
            lds[(cb + 1) * PSTR + rr] = stg[k][1];
            lds[(cb + 2) * PSTR + rr] = stg[k][2];
            lds[(cb + 3) * PSTR + rr] = stg[k][3];
        }
        __syncthreads();

        // prefetch next window while computing this one
        if (w + 1 < NWIN) {
#pragma unroll
            for (int k = 0; k < 14; ++k) {
                const int idx = k * 256 + tid;
                const int c4 = idx % 28, rr = idx / 28;
                stg[k] = x4[(long)rr * NC4 + (w + 1) * 28 + c4];
            }
        }

        const float* wch = Wih + j0 * INDIM + w * WCOLS;
#pragma unroll 4
        for (int c = 0; c < WCOLS; ++c) {
            const float xv = lds[c * PSTR + r];
#pragma unroll
            for (int jj = 0; jj < 5; ++jj)
                acc[jj] = fmaf(xv, wch[jj * INDIM + c], acc[jj]);
        }
        __syncthreads();
    }

    // padded store: jh 0 -> [0..3],[4]; jh 1 -> [8..11],[12]; 32B-aligned
    float* po = xi + (row0 + r) * XIP + jh * 8;
    f4 v; v[0] = acc[0]; v[1] = acc[1]; v[2] = acc[2]; v[3] = acc[3];
    *(f4*)po = v;
    po[4] = acc[4];
}

// ---------------------------------------------------------------------------
// Scan segment [S0, S0+SEG): h_t = relu(xi_t + h_{t-1} @ W_hh^T).
// 2 threads per batch element (xor-1 pair in-wave), 5 dims each, W columns
// permuted per thread (own dims first). Packed-FP32 dot: 5 v_pk_fma_f32 +
// horizontal add. PF=16 register ring prefetch, fully static indexing;
// tail peeled so prefetch never passes S0+SEG-1 (the produced frontier).
// h parked in / restored from hstate across segments (kernel launches).
// ---------------------------------------------------------------------------
template <int S0>
__device__ __forceinline__ void scan_seg(
    const float* __restrict__ xi, const float* __restrict__ Whh,
    float* __restrict__ out, float* __restrict__ hstate, int gid)
{
    const int b    = gid >> 1;
    const int half = gid & 1;
    const int j0   = half * 5;

    // Wp[jj][p] = ( W[j0+jj][perm(2p)], W[j0+jj][perm(2p+1)] ),
    // perm(k) = k<5 ? k+j0 : k-j0
    f2 Wp[5][5];
#pragma unroll
    for (int jj = 0; jj < 5; ++jj)
#pragma unroll
        for (int p = 0; p < 5; ++p) {
            const int k0 = 2 * p, k1 = 2 * p + 1;
            const int c0 = (k0 < 5) ? (k0 + j0) : (k0 - j0);
            const int c1 = (k1 < 5) ? (k1 + j0) : (k1 - j0);
            Wp[jj][p] = mk2(Whh[(j0 + jj) * HID + c0],
                            Whh[(j0 + jj) * HID + c1]);
        }

    f2 H[5];
    if (S0 == 0) {
#pragma unroll
        for (int p = 0; p < 5; ++p) H[p] = mk2(0.f, 0.f);
    } else {
        const float* hs = hstate + b * HID;
        float h[10];
#pragma unroll
        for (int jj = 0; jj < 5; ++jj) {
            h[jj]     = hs[j0 + jj];
            h[5 + jj] = hs[(5 - j0) + jj];
        }
        H[0] = mk2(h[0], h[1]); H[1] = mk2(h[2], h[3]);
        H[2] = mk2(h[4], h[5]); H[3] = mk2(h[6], h[7]);
        H[4] = mk2(h[8], h[9]);
    }

    const float* xib  = xi  + b * XIP + half * 8;   // 32B-aligned
    float*       outb = out + b * HID + j0;

    // fill the ring: steps S0..S0+PF-1
    float buf[PF][5];
#pragma unroll
    for (int i = 0; i < PF; ++i) {
        const float* p = xib + (long)(S0 + i) * (BATCH * XIP);
        const f4 v = *(const f4*)p;
        buf[i][0] = v[0]; buf[i][1] = v[1]; buf[i][2] = v[2]; buf[i][3] = v[3];
        buf[i][4] = p[4];
    }

    for (int t0 = S0; t0 < S0 + SEG - PF; t0 += PF) {
#pragma unroll
        for (int i = 0; i < PF; ++i) {
            const int t = t0 + i;

            float cur[5];
#pragma unroll
            for (int jj = 0; jj < 5; ++jj) cur[jj] = buf[i][jj];

            // prefetch t+PF (<= S0+SEG-1: stays inside the segment)
            {
                const float* p = xib + (long)(t + PF) * (BATCH * XIP);
                const f4 v = *(const f4*)p;
                buf[i][0] = v[0]; buf[i][1] = v[1];
                buf[i][2] = v[2]; buf[i][3] = v[3];
                buf[i][4] = p[4];
            }

            float s[5];
#pragma unroll
            for (int jj = 0; jj < 5; ++jj) {
                f2 a = mk2(cur[jj], 0.f);
#pragma unroll
                for (int q = 0; q < 5; ++q)
                    a = __builtin_elementwise_fma(Wp[jj][q], H[q], a);
                s[jj] = fmaxf(a[0] + a[1], 0.f);
            }

            float* po = outb + (long)t * (BATCH * HID);
#pragma unroll
            for (int jj = 0; jj < 5; ++jj) po[jj] = s[jj];

            float shf[5];
#pragma unroll
            for (int jj = 0; jj < 5; ++jj) shf[jj] = __shfl_xor(s[jj], 1, 64);
            H[0] = mk2(s[0],   s[1]);
            H[1] = mk2(s[2],   s[3]);
            H[2] = mk2(s[4],   shf[0]);
            H[3] = mk2(shf[1], shf[2]);
            H[4] = mk2(shf[3], shf[4]);
        }
    }

    // tail: last PF steps, ring already holds them
#pragma unroll
    for (int i = 0; i < PF; ++i) {
        const int t = S0 + SEG - PF + i;

        float s[5];
#pragma unroll
        for (int jj = 0; jj < 5; ++jj) {
            f2 a = mk2(buf[i][jj], 0.f);
#pragma unroll
            for (int q = 0; q < 5; ++q)
                a = __builtin_elementwise_fma(Wp[jj][q], H[q], a);
            s[jj] = fmaxf(a[0] + a[1], 0.f);
        }

        float* po = outb + (long)t * (BATCH * HID);
#pragma unroll
        for (int jj = 0; jj < 5; ++jj) po[jj] = s[jj];

        float shf[5];
#pragma unroll
        for (int jj = 0; jj < 5; ++jj) shf[jj] = __shfl_xor(s[jj], 1, 64);
        H[0] = mk2(s[0],   s[1]);
        H[1] = mk2(s[2],   s[3]);
        H[2] = mk2(s[4],   shf[0]);
        H[3] = mk2(shf[1], shf[2]);
        H[4] = mk2(shf[3], shf[4]);
    }

    if (S0 == 0) {
        // park own dims for the next segment (next launch)
        float* hs = hstate + b * HID;
        hs[j0 + 0] = H[0][0]; hs[j0 + 1] = H[0][1]; hs[j0 + 2] = H[1][0];
        hs[j0 + 3] = H[1][1]; hs[j0 + 4] = H[2][0];
    } else {
        // final h_n
        float* pl = out + (long)SEQ * BATCH * HID + b * HID + j0;
        pl[0] = H[0][0]; pl[1] = H[0][1]; pl[2] = H[1][0];
        pl[3] = H[1][1]; pl[4] = H[2][0];
    }
}

// ---------------------------------------------------------------------------
// L1: produce xi rows 0..65535 (t = 0..255). 512 blocks -> 2 blocks/CU.
// ---------------------------------------------------------------------------
__global__ __launch_bounds__(256) void produce0_kernel(
    const float* __restrict__ x, const float* __restrict__ Wih,
    const float* __restrict__ bih, const float* __restrict__ bhh,
    float* __restrict__ xi)
{
    __shared__ float lds[WCOLS * PSTR];   // 57.8 KB -> 2 blocks/CU
    produce_half(x, Wih, bih, bhh, xi, lds, (long)blockIdx.x * HROWS);
}

// ---------------------------------------------------------------------------
// L2: blocks 0,1 scan t = 0..255 (xi complete from L1; coherence via the
// kernel boundary) while blocks 2..513 produce xi for t = 256..511 at
// 2 blocks/CU. Scan (~12-20us) hides under production (~38us). Scan
// reads/prefetches never pass t=255 (segment-peeled ring).
// ---------------------------------------------------------------------------
__global__ __launch_bounds__(256) void mixed_kernel(
    const float* __restrict__ x, const float* __restrict__ Wih,
    const float* __restrict__ bih, const float* __restrict__ bhh,
    float* __restrict__ xi, const float* __restrict__ Whh,
    float* __restrict__ out, float* __restrict__ hstate)
{
    __shared__ float lds[WCOLS * PSTR];
    if (blockIdx.x < 2) {
        scan_seg<0>(xi, Whh, out, hstate, (int)blockIdx.x * 256 + threadIdx.x);
    } else {
        const int pid = (int)blockIdx.x - 2;          // 0..511
        produce_half(x, Wih, bih, bhh, xi, lds,
                     (long)SEG * BATCH + (long)pid * HROWS);
    }
}

// ---------------------------------------------------------------------------
// L3: scan t = 256..511 (xi complete from L2). 8 blocks x 64 threads: one
// wave per CU, no LDS-pipe contention on the shfl swizzles.
// ---------------------------------------------------------------------------
__global__ __launch_bounds__(64) void scan1_kernel(
    const float* __restrict__ xi, const float* __restrict__ Whh,
    float* __restrict__ out, float* __restrict__ hstate)
{
    scan_seg<SEG>(xi, Whh, out, hstate,
                  (int)blockIdx.x * 64 + threadIdx.x);
}

// ---------------------------------------------------------------------------
extern "C" void kernel_launch(void* const* d_in, const int* in_sizes, int n_in,
                              void* d_out, int out_size, void* d_ws, size_t ws_size,
                              hipStream_t stream)
{
    const float* x   = (const float*)d_in[0];
    const float* Wih = (const float*)d_in[1];
    const float* Whh = (const float*)d_in[2];
    const float* bih = (const float*)d_in[3];
    const float* bhh = (const float*)d_in[4];
    float* out = (float*)d_out;
    float* xi  = (float*)d_ws;                       // SEQ*BATCH*XIP = 8.39 MB
    float* hstate = xi + (long)SEQ * BATCH * XIP;    // 2560 floats

    produce0_kernel<<<512, 256, 0, stream>>>(x, Wih, bih, bhh, xi);
    mixed_kernel<<<514, 256, 0, stream>>>(x, Wih, bih, bhh, xi, Whh, out, hstate);
    scan1_kernel<<<8, 64, 0, stream>>>(xi, Whh, out, hstate);
}

// Round 6
// 633.202 us; speedup vs baseline: 1.1727x; 1.1727x over previous
//
#include <hip/hip_runtime.h>

#define SEQ   512
#define BATCH 256
#define INDIM 784
#define HID   10
#define NC4   196   // INDIM / 4
#define CHUNK 56    // columns staged per LDS window (784 = 14 * 56)
#define NCH   14
#define STR   257   // LDS row stride in floats (odd -> <=2-way bank aliasing)
#define PF    16    // scan prefetch depth (steps)
#define XIP   16    // padded xi row stride (floats)

typedef float f4 __attribute__((ext_vector_type(4)));
typedef float f2 __attribute__((ext_vector_type(2)));

static __device__ __forceinline__ f2 mk2(float a, float b) {
    f2 r; r[0] = a; r[1] = b; return r;
}

// ---------------------------------------------------------------------------
// Kernel 1: xi[row][j] = x[row] . W_ih[j] + b_ih[j] + b_hh[j],  row = t*B+b.
// Round-3 structure (lane-per-row, block = one timestep, 2 blocks/CU,
// block-uniform W -> scalar SMEM loads) with ONE change: CHUNK-PAIR staging.
//
// Fetch theory: x rows are 3136B = 24.5 cache lines. 224B windows span
// 2-3 lines (avg 2.5 -> 1.43x fetch); the boundary halves belong to the
// adjacent chunk read ~6us later (beyond L2 lifetime at stream rate).
// Staging TWO chunks per prefetch phase (28 f4/thread), with both 224B
// half-runs of each row issued back-to-back, merges the shared boundary
// line in L2 MSHRs -> effective 448B granules -> always exactly 4 lines
// (row phases alternate 0/64 since 3136 mod 128 = 64) -> ~1.12x fetch.
// LDS window stays 56 cols (57.5KB, 2 blocks/CU); barrier count unchanged;
// column summation order unchanged -> bitwise-identical results.
// ---------------------------------------------------------------------------
__global__ __launch_bounds__(256) void xproj_kernel(
    const float* __restrict__ x, const float* __restrict__ Wih,
    const float* __restrict__ bih, const float* __restrict__ bhh,
    float* __restrict__ xi)
{
    __shared__ float lds[CHUNK * STR];   // 57,568 B -> 2 blocks/CU

    const int tid  = threadIdx.x;
    const long row0 = (long)blockIdx.x * 256;
    const f4* x4 = (const f4*)x + row0 * NC4;

    float acc[HID];
#pragma unroll
    for (int j = 0; j < HID; ++j) acc[j] = bih[j] + bhh[j];

    // stg[0..13] = even chunk, stg[14..27] = odd chunk of the current pair.
    f4 stg[28];
    // preload pair 0 (chunks 0,1): both halves issued back-to-back
#pragma unroll
    for (int k = 0; k < 28; ++k) {
        const int h = k / 14, kk = k % 14;
        const int idx = kk * 256 + tid;
        const int c4 = idx % 14, r = idx / 14;
        stg[k] = x4[(long)r * NC4 + h * 14 + c4];
    }

    for (int cp = 0; cp < 7; ++cp) {    // chunk pair: chunks 2cp, 2cp+1
        // ---- even chunk: regs 0..13 -> LDS, transposed
#pragma unroll
        for (int k = 0; k < 14; ++k) {
            const int idx = k * 256 + tid;
            const int c4 = idx % 14, r = idx / 14;
            const int cb = c4 * 4;
            lds[(cb + 0) * STR + r] = stg[k][0];
            lds[(cb + 1) * STR + r] = stg[k][1];
            lds[(cb + 2) * STR + r] = stg[k][2];
            lds[(cb + 3) * STR + r] = stg[k][3];
        }
        __syncthreads();

        {
            const float* wch = Wih + (2 * cp) * CHUNK;
#pragma unroll 4
            for (int c = 0; c < CHUNK; ++c) {
                const float xv = lds[c * STR + tid];
#pragma unroll
                for (int j = 0; j < HID; ++j)
                    acc[j] = fmaf(xv, wch[j * INDIM + c], acc[j]);
            }
        }
        __syncthreads();

        // ---- odd chunk: regs 14..27 -> LDS, transposed
#pragma unroll
        for (int k = 0; k < 14; ++k) {
            const int idx = k * 256 + tid;
            const int c4 = idx % 14, r = idx / 14;
            const int cb = c4 * 4;
            lds[(cb + 0) * STR + r] = stg[14 + k][0];
            lds[(cb + 1) * STR + r] = stg[14 + k][1];
            lds[(cb + 2) * STR + r] = stg[14 + k][2];
            lds[(cb + 3) * STR + r] = stg[14 + k][3];
        }
        __syncthreads();

        // prefetch next pair (28 loads clustered: 448B-granule fetches),
        // overlapping the odd-chunk compute. WAR on stg is safe: the
        // ds_writes above read the regs at issue, before the loads land.
        if (cp + 1 < 7) {
#pragma unroll
            for (int k = 0; k < 28; ++k) {
                const int h = k / 14, kk = k % 14;
                const int idx = kk * 256 + tid;
                const int c4 = idx % 14, r = idx / 14;
                stg[k] = x4[(long)r * NC4 + (cp + 1) * 28 + h * 14 + c4];
            }
        }

        {
            const float* wch = Wih + (2 * cp + 1) * CHUNK;
#pragma unroll 4
            for (int c = 0; c < CHUNK; ++c) {
                const float xv = lds[c * STR + tid];
#pragma unroll
                for (int j = 0; j < HID; ++j)
                    acc[j] = fmaf(xv, wch[j * INDIM + c], acc[j]);
            }
        }
        __syncthreads();
    }

    // padded store: [0..3],[4] and [8..11],[12]; rows 64B apart -> coalesced
    float* po = xi + (row0 + tid) * XIP;
    f4 lo; lo[0] = acc[0]; lo[1] = acc[1]; lo[2] = acc[2]; lo[3] = acc[3];
    f4 hi; hi[0] = acc[5]; hi[1] = acc[6]; hi[2] = acc[7]; hi[3] = acc[8];
    *(f4*)po = lo;        po[4]  = acc[4];
    *(f4*)(po + 8) = hi;  po[12] = acc[9];
}

// ---------------------------------------------------------------------------
// Kernel 2 (verbatim round 3): h_t = relu(xi_t + h_{t-1} @ W_hh^T).
// 2 threads per batch element (xor-1 pair in-wave), 5 dims each; W columns
// permuted per thread (own dims first -> static h indexing). Packed-FP32
// dot: 5 v_pk_fma_f32 + horizontal add. PF=16 register ring prefetch of the
// padded xi (dwordx4+dword per step), fully static indexing, tail peeled.
// 8 blocks x 64 threads: one wave per CU.
// ---------------------------------------------------------------------------
__global__ __launch_bounds__(64) void scan_kernel(
    const float* __restrict__ xi, const float* __restrict__ Whh,
    float* __restrict__ out)
{
    const int gid  = blockIdx.x * 64 + threadIdx.x;    // 0..511
    const int b    = gid >> 1;
    const int half = gid & 1;
    const int j0   = half * 5;

    // Wp[jj][p] = ( W[j0+jj][perm(2p)], W[j0+jj][perm(2p+1)] ),
    // perm(k) = k<5 ? k+j0 : k-j0
    f2 Wp[5][5];
#pragma unroll
    for (int jj = 0; jj < 5; ++jj)
#pragma unroll
        for (int p = 0; p < 5; ++p) {
            const int k0 = 2 * p, k1 = 2 * p + 1;
            const int c0 = (k0 < 5) ? (k0 + j0) : (k0 - j0);
            const int c1 = (k1 < 5) ? (k1 + j0) : (k1 - j0);
            Wp[jj][p] = mk2(Whh[(j0 + jj) * HID + c0],
                            Whh[(j0 + jj) * HID + c1]);
        }

    f2 H[5];
#pragma unroll
    for (int p = 0; p < 5; ++p) H[p] = mk2(0.f, 0.f);

    const float* xib  = xi  + b * XIP + half * 8;   // 32B-aligned
    float*       outb = out + b * HID + j0;

    // fill the ring: steps 0..PF-1
    float buf[PF][5];
#pragma unroll
    for (int i = 0; i < PF; ++i) {
        const float* p = xib + (long)i * (BATCH * XIP);
        const f4 v = *(const f4*)p;
        buf[i][0] = v[0]; buf[i][1] = v[1]; buf[i][2] = v[2]; buf[i][3] = v[3];
        buf[i][4] = p[4];
    }

    for (int t0 = 0; t0 < SEQ - PF; t0 += PF) {
#pragma unroll
        for (int i = 0; i < PF; ++i) {
            const int t = t0 + i;

            float cur[5];
#pragma unroll
            for (int jj = 0; jj < 5; ++jj) cur[jj] = buf[i][jj];

            // issue prefetch for t+PF immediately (full window)
            {
                const float* p = xib + (long)(t + PF) * (BATCH * XIP);
                const f4 v = *(const f4*)p;
                buf[i][0] = v[0]; buf[i][1] = v[1];
                buf[i][2] = v[2]; buf[i][3] = v[3];
                buf[i][4] = p[4];
            }

            float s[5];
#pragma unroll
            for (int jj = 0; jj < 5; ++jj) {
                f2 a = mk2(cur[jj], 0.f);
#pragma unroll
                for (int q = 0; q < 5; ++q)
                    a = __builtin_elementwise_fma(Wp[jj][q], H[q], a);
                s[jj] = fmaxf(a[0] + a[1], 0.f);
            }

            float* po = outb + (long)t * (BATCH * HID);
#pragma unroll
            for (int jj = 0; jj < 5; ++jj) po[jj] = s[jj];

            float shf[5];
#pragma unroll
            for (int jj = 0; jj < 5; ++jj) shf[jj] = __shfl_xor(s[jj], 1, 64);
            H[0] = mk2(s[0],   s[1]);
            H[1] = mk2(s[2],   s[3]);
            H[2] = mk2(s[4],   shf[0]);
            H[3] = mk2(shf[1], shf[2]);
            H[4] = mk2(shf[3], shf[4]);
        }
    }

    // tail: last PF steps, ring already holds them, no prefetch
#pragma unroll
    for (int i = 0; i < PF; ++i) {
        const int t = SEQ - PF + i;

        float s[5];
#pragma unroll
        for (int jj = 0; jj < 5; ++jj) {
            f2 a = mk2(buf[i][jj], 0.f);
#pragma unroll
            for (int q = 0; q < 5; ++q)
                a = __builtin_elementwise_fma(Wp[jj][q], H[q], a);
            s[jj] = fmaxf(a[0] + a[1], 0.f);
        }

        float* po = outb + (long)t * (BATCH * HID);
#pragma unroll
        for (int jj = 0; jj < 5; ++jj) po[jj] = s[jj];

        float shf[5];
#pragma unroll
        for (int jj = 0; jj < 5; ++jj) shf[jj] = __shfl_xor(s[jj], 1, 64);
        H[0] = mk2(s[0],   s[1]);
        H[1] = mk2(s[2],   s[3]);
        H[2] = mk2(s[4],   shf[0]);
        H[3] = mk2(shf[1], shf[2]);
        H[4] = mk2(shf[3], shf[4]);
    }

    // h_n: this thread owns dims j0..j0+4 = H[0..2] lo/hi halves
    float* pl = out + (long)SEQ * BATCH * HID + b * HID + j0;
    pl[0] = H[0][0]; pl[1] = H[0][1]; pl[2] = H[1][0];
    pl[3] = H[1][1]; pl[4] = H[2][0];
}

// ---------------------------------------------------------------------------
extern "C" void kernel_launch(void* const* d_in, const int* in_sizes, int n_in,
                              void* d_out, int out_size, void* d_ws, size_t ws_size,
                              hipStream_t stream)
{
    const float* x   = (const float*)d_in[0];
    const float* Wih = (const float*)d_in[1];
    const float* Whh = (const float*)d_in[2];
    const float* bih = (const float*)d_in[3];
    const float* bhh = (const float*)d_in[4];
    float* out = (float*)d_out;
    float* xi  = (float*)d_ws;   // SEQ*BATCH*XIP floats = 8.39 MB (padded)

    xproj_kernel<<<512, 256, 0, stream>>>(x, Wih, bih, bhh, xi);
    scan_kernel<<<8, 64, 0, stream>>>(xi, Whh, out);
}